// Round 13
// baseline (174.472 us; speedup 1.0000x reference)
//
#include <hip/hip_runtime.h>
#include <hip/hip_bf16.h>
#include <stdint.h>

#define NN 8192
#define FIN 512
#define FOUT 256
#define ALPHAV 0.2f
#define MASKF 9e-15f
#define L2E 1.44269504088896340736f

typedef __attribute__((ext_vector_type(8))) short bf16x8;
typedef __attribute__((ext_vector_type(16))) float f32x16;

static __device__ __forceinline__ float ex2(float x){
#if __has_builtin(__builtin_amdgcn_exp2f)
  return __builtin_amdgcn_exp2f(x);
#else
  return exp2f(x);
#endif
}
static __device__ __forceinline__ unsigned short f2bf(float f){
  __bf16 b = (__bf16)f;
  return __builtin_bit_cast(unsigned short, b);
}
static __device__ __forceinline__ float bf2f(unsigned short u){
  unsigned int v = ((unsigned int)u) << 16;
  return __builtin_bit_cast(float, v);
}

// ---------------- K0: W(512x256 f32) -> Wt hi/lo, step-tiled bf16 ---------
__global__ __launch_bounds__(256) void k_prep(
    const float* __restrict__ Wm, unsigned short* __restrict__ WtHi,
    unsigned short* __restrict__ WtLo)
{
  __shared__ float ls[16 * 256];
  const int t = threadIdx.x;
  const int S = blockIdx.x;          // kstep 0..31
  const int k0 = S * 16;
  {
    const int kk = t >> 4;
    const int n0 = (t & 15) * 16;
#pragma unroll
    for (int q = 0; q < 4; ++q) {
      float4 v = *(const float4*)(Wm + (size_t)(k0 + kk) * FOUT + n0 + q * 4);
      *(float4*)(&ls[kk * 256 + n0 + q * 4]) = v;
    }
  }
  __syncthreads();
  float v[16];
  unsigned short hh[16], ll[16];
#pragma unroll
  for (int kk = 0; kk < 16; ++kk) {
    v[kk] = ls[kk * 256 + t];
    hh[kk] = f2bf(v[kk]);
    ll[kk] = f2bf(v[kk] - bf2f(hh[kk]));
  }
  unsigned short* oh = WtHi + (size_t)S * 4096 + t * 8;
  unsigned short* ol = WtLo + (size_t)S * 4096 + t * 8;
#pragma unroll
  for (int g = 0; g < 2; ++g) {      // kg 0/1
    ushort4 a, b, c, d;
    a.x = hh[g*8+0]; a.y = hh[g*8+1]; a.z = hh[g*8+2]; a.w = hh[g*8+3];
    b.x = hh[g*8+4]; b.y = hh[g*8+5]; b.z = hh[g*8+6]; b.w = hh[g*8+7];
    c.x = ll[g*8+0]; c.y = ll[g*8+1]; c.z = ll[g*8+2]; c.w = ll[g*8+3];
    d.x = ll[g*8+4]; d.y = ll[g*8+5]; d.z = ll[g*8+6]; d.w = ll[g*8+7];
    *(ushort4*)(oh + g * 2048)     = a;
    *(ushort4*)(oh + g * 2048 + 4) = b;
    *(ushort4*)(ol + g * 2048)     = c;
    *(ushort4*)(ol + g * 2048 + 4) = d;
  }
}

// ---------------- K1: hTt = (x@W)^T via 32x32x16 MFMA, hi/lo split --------
// (unchanged from R12 — measured ~6 µs)
__global__ __launch_bounds__(256, 1) void k_gemm_h(
    const float* __restrict__ x, const unsigned short* __restrict__ WtHi,
    const unsigned short* __restrict__ WtLo, const float* __restrict__ aG,
    unsigned short* __restrict__ hTt, float* __restrict__ f1,
    float* __restrict__ f2)
{
  __shared__ __align__(16) unsigned short xhi[16384];
  __shared__ __align__(16) unsigned short xlo[16384];
  __shared__ __align__(16) unsigned short wsh[3][4096];
  __shared__ __align__(16) unsigned short wsl[3][4096];
  __shared__ __align__(16) float as2[512];
  __shared__ float f1red[4][32], f2red[4][32];

  const int t  = threadIdx.x;
  const int wv = t >> 6;
  const int l  = t & 63;
  const int lh = l >> 5;
  const int lm = l & 31;
  const int i0 = blockIdx.x * 32;

  if (t < 128) {
    float4 v = *(const float4*)(aG + t * 4);
    *(float4*)(&as2[t * 4]) = v;
  }
  {
    const int xi = t >> 3;
    const int kb = (t & 7) * 4;
    const float* xrow = x + (size_t)(i0 + xi) * FIN;
    const int kgb = (t & 7) >> 1;
    const int bo  = (t & 1) * 4;
#pragma unroll
    for (int q = 0; q < 16; ++q) {
      float4 v = *(const float4*)(xrow + kb + q * 32);
      ushort4 h4, l4;
      h4.x = f2bf(v.x); l4.x = f2bf(v.x - bf2f(h4.x));
      h4.y = f2bf(v.y); l4.y = f2bf(v.y - bf2f(h4.y));
      h4.z = f2bf(v.z); l4.z = f2bf(v.z - bf2f(h4.z));
      h4.w = f2bf(v.w); l4.w = f2bf(v.w - bf2f(h4.w));
      const int idx = (q * 4 + kgb) * 256 + xi * 8 + bo;
      *(ushort4*)(&xhi[idx]) = h4;
      *(ushort4*)(&xlo[idx]) = l4;
    }
  }

  f32x16 acc0, acc1;
#pragma unroll
  for (int e = 0; e < 16; ++e) { acc0[e] = 0.f; acc1[e] = 0.f; }

#define SB0 __builtin_amdgcn_sched_barrier(0)
#define WSTAGE(B, S)                                                          \
  do {                                                                        \
    const unsigned short* gh_ = WtHi + (size_t)(S) * 4096 + t * 8;            \
    const unsigned short* gl_ = WtLo + (size_t)(S) * 4096 + t * 8;            \
    __builtin_amdgcn_global_load_lds(                                         \
        (const __attribute__((address_space(1))) unsigned int*)gh_,           \
        (__attribute__((address_space(3))) unsigned int*)(&wsh[B][t * 8]), 16, 0, 0); \
    __builtin_amdgcn_global_load_lds(                                         \
        (const __attribute__((address_space(1))) unsigned int*)(gh_ + 2048),  \
        (__attribute__((address_space(3))) unsigned int*)(&wsh[B][2048 + t * 8]), 16, 0, 0); \
    __builtin_amdgcn_global_load_lds(                                         \
        (const __attribute__((address_space(1))) unsigned int*)gl_,           \
        (__attribute__((address_space(3))) unsigned int*)(&wsl[B][t * 8]), 16, 0, 0); \
    __builtin_amdgcn_global_load_lds(                                         \
        (const __attribute__((address_space(1))) unsigned int*)(gl_ + 2048),  \
        (__attribute__((address_space(3))) unsigned int*)(&wsl[B][2048 + t * 8]), 16, 0, 0); \
  } while (0)

#define GTS(S, BUF, DOISSUE, NBUF, VMC)                                       \
  do {                                                                        \
    asm volatile("s_waitcnt vmcnt(" #VMC ")" ::: "memory");                   \
    __builtin_amdgcn_s_barrier();                                             \
    SB0;                                                                      \
    if (DOISSUE) WSTAGE(NBUF, (S) + 2);                                       \
    SB0;                                                                      \
    const int kgb_ = ((S) * 2 + lh) * 512 + lm * 16;                          \
    bf16x8 bh_ = *(const bf16x8*)(((const char*)xhi) + kgb_);                 \
    bf16x8 bl_ = *(const bf16x8*)(((const char*)xlo) + kgb_);                 \
    const int na_ = lh * 4096 + (wv * 64 + lm) * 16;                          \
    bf16x8 ah0_ = *(const bf16x8*)(((const char*)&wsh[BUF][0]) + na_);        \
    bf16x8 al0_ = *(const bf16x8*)(((const char*)&wsl[BUF][0]) + na_);        \
    bf16x8 ah1_ = *(const bf16x8*)(((const char*)&wsh[BUF][0]) + na_ + 512);  \
    bf16x8 al1_ = *(const bf16x8*)(((const char*)&wsl[BUF][0]) + na_ + 512);  \
    acc0 = __builtin_amdgcn_mfma_f32_32x32x16_bf16(ah0_, bh_, acc0, 0, 0, 0); \
    acc1 = __builtin_amdgcn_mfma_f32_32x32x16_bf16(ah1_, bh_, acc1, 0, 0, 0); \
    acc0 = __builtin_amdgcn_mfma_f32_32x32x16_bf16(ah0_, bl_, acc0, 0, 0, 0); \
    acc1 = __builtin_amdgcn_mfma_f32_32x32x16_bf16(ah1_, bl_, acc1, 0, 0, 0); \
    acc0 = __builtin_amdgcn_mfma_f32_32x32x16_bf16(al0_, bh_, acc0, 0, 0, 0); \
    acc1 = __builtin_amdgcn_mfma_f32_32x32x16_bf16(al1_, bh_, acc1, 0, 0, 0); \
  } while (0)

  asm volatile("s_waitcnt vmcnt(0)" ::: "memory");
  SB0;
  WSTAGE(0, 0);
  SB0;
  WSTAGE(1, 1);
  asm volatile("s_waitcnt lgkmcnt(0)" ::: "memory");
  SB0;

#pragma unroll 1
  for (int p = 0; p < 10; ++p) {
    const int s0 = p * 3;
    GTS(s0 + 0, 0, 1, 2, 4);
    GTS(s0 + 1, 1, 1, 0, 4);
    GTS(s0 + 2, 2, 1, 1, 4);
  }
  GTS(30, 0, 0, 2, 4);
  GTS(31, 1, 0, 0, 0);
#undef SB0
#undef WSTAGE
#undef GTS

  float p1 = 0.f, p2 = 0.f;
#pragma unroll
  for (int reg = 0; reg < 16; ++reg) {
    const int nl = (reg & 3) + 8 * (reg >> 2) + 4 * lh;
    p1 += acc0[reg] * as2[wv * 64 + nl]       + acc1[reg] * as2[wv * 64 + 32 + nl];
    p2 += acc0[reg] * as2[256 + wv * 64 + nl] + acc1[reg] * as2[256 + wv * 64 + 32 + nl];
  }
  p1 += __shfl_xor(p1, 32);
  p2 += __shfl_xor(p2, 32);
  if (l < 32) { f1red[wv][l] = p1; f2red[wv][l] = p2; }
  __syncthreads();
  if (t < 32) {
    f1[i0 + t] = f1red[0][t] + f1red[1][t] + f1red[2][t] + f1red[3][t];
    f2[i0 + t] = f2red[0][t] + f2red[1][t] + f2red[2][t] + f2red[3][t];
  }

  const size_t hb = (size_t)(i0 >> 5) * 8192 + (size_t)(lm >> 3) * 2048 + (lm & 7);
#pragma unroll
  for (int reg = 0; reg < 16; ++reg) {
    const int nl = (reg & 3) + 8 * (reg >> 2) + 4 * lh;
    hTt[hb + (size_t)(wv * 64 + nl) * 8]      = f2bf(acc0[reg]);
    hTt[hb + (size_t)(wv * 64 + 32 + nl) * 8] = f2bf(acc1[reg]);
  }
}

// ---------------- K2: row-max UPPER BOUND m̂_i = lrelu(f1_i + max f2) ------
__global__ __launch_bounds__(1024) void k_bound(
    const float* __restrict__ f1, const float* __restrict__ f2,
    float* __restrict__ mhat)
{
  __shared__ float red[16];
  const int t = threadIdx.x;
  float m = -3.0e38f;
#pragma unroll
  for (int k = 0; k < 8; ++k) m = fmaxf(m, f2[t + k * 1024]);
#pragma unroll
  for (int off = 32; off > 0; off >>= 1) m = fmaxf(m, __shfl_xor(m, off));
  if ((t & 63) == 0) red[t >> 6] = m;
  __syncthreads();
  float fm = red[0];
#pragma unroll
  for (int w = 1; w < 16; ++w) fm = fmaxf(fm, red[w]);
#pragma unroll
  for (int k = 0; k < 8; ++k) {
    int i = t + k * 1024;
    float s = f1[i] + fm;
    mhat[i] = fmaxf(fmaxf(s, ALPHAV * s), MASKF);
  }
}

// ---------------- K3: adj STREAMED THROUGH the MFMA pipeline --------------
// Per step: load 4 int4 adj (window jt+4) into X/Y regs; convert the set
// loaded 2 steps ago to 16 bits, shfl-combine, write u32/row to a 4-slot
// LDS mask ring (consumed 2 barriers later). Counted stream = 8 vmem/step
// (4 stage + 4 adj), vmcnt(8) steady / 4,4,0 tail. HBM adj streaming now
// overlaps LDS/MFMA for the whole loop. grid (64,8), 2 blocks/CU.
__global__ __launch_bounds__(256, 2) void k_spmm(
    const unsigned short* __restrict__ hTt,
    const int* __restrict__ adj,
    const float* __restrict__ f1, const float* __restrict__ f2,
    const float* __restrict__ mhat,
    float* __restrict__ part, float* __restrict__ rowsumP)
{
  __shared__ __align__(16) unsigned short hbuf[3 * 8192]; // 3 x 16 KB
  __shared__ __align__(16) unsigned int mskR[4][128];     // mask ring, 2 KB
  __shared__ __align__(16) float f2s[1024];               // pre-scaled by L2E
  const int t  = threadIdx.x;
  const int wv = t >> 6;
  const int l  = t & 63;
  const int lh = l >> 5;
  const int lm = l & 31;
  const int bx = blockIdx.x;
  const int ks = blockIdx.y;
  const int r0 = bx * 128;
  const int lh8 = lh * 8;

  const int rA = r0 + wv * 32 + lm;
  const float nmA   = -mhat[rA] * L2E;
  const float base0 = fmaf(f1[rA], L2E, nmA);
  const float c20   = nmA * (1.f - ALPHAV);
  const float mc0   = fmaf(MASKF, L2E, nmA);

  // adj gather base: thread pair (2k,2k+1) covers row k's 32-int window,
  // halves by t&1 (16 ints = 4 int4 contiguous per thread).
  const int* aQ = adj + (size_t)(r0 + (t >> 1)) * NN + ks * 1024 + (t & 1) * 16;

  // f2 slice -> LDS (pre-scaled)
  {
    float4 v = *(const float4*)(f2 + ks * 1024 + t * 4);
    v.x *= L2E; v.y *= L2E; v.z *= L2E; v.w *= L2E;
    *(float4*)(&f2s[t * 4]) = v;
  }

#define SB0 __builtin_amdgcn_sched_barrier(0)
#define CONV(R0, R1, R2, R3, SLOT)                                            \
  do {                                                                        \
    unsigned int mb_ = 0;                                                     \
    mb_ |= (R0.x > 0 ? 1u : 0u) << 0;  mb_ |= (R0.y > 0 ? 1u : 0u) << 1;      \
    mb_ |= (R0.z > 0 ? 1u : 0u) << 2;  mb_ |= (R0.w > 0 ? 1u : 0u) << 3;      \
    mb_ |= (R1.x > 0 ? 1u : 0u) << 4;  mb_ |= (R1.y > 0 ? 1u : 0u) << 5;      \
    mb_ |= (R1.z > 0 ? 1u : 0u) << 6;  mb_ |= (R1.w > 0 ? 1u : 0u) << 7;      \
    mb_ |= (R2.x > 0 ? 1u : 0u) << 8;  mb_ |= (R2.y > 0 ? 1u : 0u) << 9;      \
    mb_ |= (R2.z > 0 ? 1u : 0u) << 10; mb_ |= (R2.w > 0 ? 1u : 0u) << 11;     \
    mb_ |= (R3.x > 0 ? 1u : 0u) << 12; mb_ |= (R3.y > 0 ? 1u : 0u) << 13;     \
    mb_ |= (R3.z > 0 ? 1u : 0u) << 14; mb_ |= (R3.w > 0 ? 1u : 0u) << 15;     \
    unsigned int ob_ = __shfl_xor(mb_, 1);                                    \
    if (!(t & 1)) mskR[SLOT][t >> 1] = mb_ | (ob_ << 16);                     \
  } while (0)

#define ADJR(R0, R1, R2, R3, W)                                               \
  do {                                                                        \
    R0 = *(const int4*)(aQ + (W) * 32);                                       \
    R1 = *(const int4*)(aQ + (W) * 32 + 4);                                   \
    R2 = *(const int4*)(aQ + (W) * 32 + 8);                                   \
    R3 = *(const int4*)(aQ + (W) * 32 + 12);                                  \
  } while (0)

#define STAGE(BUFI, JT)                                                       \
  do {                                                                        \
    const unsigned short* gp_ = hTt + (size_t)ks * 32 * 8192                  \
                                + (size_t)(JT) * 8192 + t * 8;                \
    char* lp_ = ((char*)hbuf) + (BUFI) * 16384 + t * 16;                      \
    _Pragma("unroll")                                                         \
    for (int c = 0; c < 4; ++c) {                                             \
      __builtin_amdgcn_global_load_lds(                                       \
          (const __attribute__((address_space(1))) unsigned int*)(gp_ + c * 2048), \
          (__attribute__((address_space(3))) unsigned int*)(lp_ + c * 4096),  \
          16, 0, 0);                                                          \
    }                                                                         \
  } while (0)

#define REGEN8(AFR, MB, FB)                                                   \
  do {                                                                        \
    float4 fx_ = *(const float4*)(&f2s[FB]);                                  \
    float4 fy_ = *(const float4*)(&f2s[(FB) + 4]);                            \
    float fv_[8] = {fx_.x, fx_.y, fx_.z, fx_.w, fy_.x, fy_.y, fy_.z, fy_.w};  \
    _Pragma("unroll")                                                         \
    for (int b = 0; b < 8; ++b) {                                             \
      float u_ = base0 + fv_[b];                                              \
      float w_ = fmaxf(u_, fmaf(ALPHAV, u_, c20));                            \
      w_ = (((MB) >> b) & 1u) ? w_ : mc0;                                     \
      float p_ = ex2(w_);                                                     \
      sumP += p_;                                                             \
      AFR[b] = (short)f2bf(p_);                                               \
    }                                                                         \
  } while (0)

#define TS(JT, BUF, NBUF, R0, R1, R2, R3, DOCONV, DOSTAGE, DOADJ, VMC)        \
  do {                                                                        \
    asm volatile("s_waitcnt vmcnt(" #VMC ")" ::: "memory");                   \
    __builtin_amdgcn_s_barrier();                                             \
    SB0;                                                                      \
    if (DOCONV) CONV(R0, R1, R2, R3, ((JT) + 2) & 3);                         \
    if (DOSTAGE) STAGE(NBUF, (JT) + 2);                                       \
    if (DOADJ) ADJR(R0, R1, R2, R3, (JT) + 4);                                \
    SB0;                                                                      \
    const unsigned int m_ = mskR[(JT) & 3][mrow];                             \
    bf16x8 afr0_, afr1_;                                                      \
    REGEN8(afr0_, m_ >> lh8,        (JT) * 32 + lh8);                         \
    REGEN8(afr1_, m_ >> (16 + lh8), (JT) * 32 + 16 + lh8);                    \
    SB0;                                                                      \
    const char* lb_ = cbase + (BUF) * 16384;                                  \
    const int g0_ = lh * 4096;                                                \
    const int g1_ = (2 + lh) * 4096;                                          \
    const int cb_ = lm * 16;                                                  \
    _Pragma("unroll")                                                         \
    for (int c = 0; c < 8; ++c) {                                             \
      bf16x8 b0_ = *(const bf16x8*)(lb_ + g0_ + c * 512 + cb_);               \
      acc[c] = __builtin_amdgcn_mfma_f32_32x32x16_bf16(afr0_, b0_, acc[c], 0, 0, 0); \
      bf16x8 b1_ = *(const bf16x8*)(lb_ + g1_ + c * 512 + cb_);               \
      acc[c] = __builtin_amdgcn_mfma_f32_32x32x16_bf16(afr1_, b1_, acc[c], 0, 0, 0); \
    }                                                                         \
  } while (0)

  // direct masks for steps 0,1 (ordinary loads; compiler inserts waits)
  {
    int4 a0 = *(const int4*)(aQ + 0),  a1 = *(const int4*)(aQ + 4);
    int4 a2 = *(const int4*)(aQ + 8),  a3 = *(const int4*)(aQ + 12);
    CONV(a0, a1, a2, a3, 0);
    int4 b0 = *(const int4*)(aQ + 32), b1 = *(const int4*)(aQ + 36);
    int4 b2 = *(const int4*)(aQ + 40), b3 = *(const int4*)(aQ + 44);
    CONV(b0, b1, b2, b3, 1);
  }
  SB0;

  f32x16 acc[8];
#pragma unroll
  for (int c = 0; c < 8; ++c)
#pragma unroll
    for (int e = 0; e < 16; ++e) acc[c][e] = 0.f;
  float sumP = 0.f;

  const char* cbase = (const char*)hbuf;
  const int mrow = wv * 32 + lm;

  int4 X0, X1, X2, X3, Y0, Y1, Y2, Y3;

  // counted prologue stream (steps -2,-1): [stage(0),X(w2)] [stage(1),Y(w3)]
  STAGE(0, 0);
  ADJR(X0, X1, X2, X3, 2);
  SB0;
  STAGE(1, 1);
  ADJR(Y0, Y1, Y2, Y3, 3);
  asm volatile("s_waitcnt lgkmcnt(0)" ::: "memory");  // mskR[0,1] + f2s writes
  SB0;

#pragma unroll 1
  for (int p = 0; p < 4; ++p) {
    const int s0 = p * 6;
    TS(s0 + 0, 0, 2, X0, X1, X2, X3, 1, 1, 1, 8);
    TS(s0 + 1, 1, 0, Y0, Y1, Y2, Y3, 1, 1, 1, 8);
    TS(s0 + 2, 2, 1, X0, X1, X2, X3, 1, 1, 1, 8);
    TS(s0 + 3, 0, 2, Y0, Y1, Y2, Y3, 1, 1, 1, 8);
    TS(s0 + 4, 1, 0, X0, X1, X2, X3, 1, 1, 1, 8);
    TS(s0 + 5, 2, 1, Y0, Y1, Y2, Y3, 1, 1, 1, 8);
  }
  TS(24, 0, 2, X0, X1, X2, X3, 1, 1, 1, 8);
  TS(25, 1, 0, Y0, Y1, Y2, Y3, 1, 1, 1, 8);
  TS(26, 2, 1, X0, X1, X2, X3, 1, 1, 1, 8);
  TS(27, 0, 2, Y0, Y1, Y2, Y3, 1, 1, 1, 8);
  TS(28, 1, 0, X0, X1, X2, X3, 1, 1, 0, 8);  // conv X(w30), stage(30)
  TS(29, 2, 1, Y0, Y1, Y2, Y3, 1, 1, 0, 4);  // conv Y(w31), stage(31)
  TS(30, 0, 2, X0, X1, X2, X3, 0, 0, 0, 4);
  TS(31, 1, 0, Y0, Y1, Y2, Y3, 0, 0, 0, 0);

#undef SB0
#undef CONV
#undef ADJR
#undef STAGE
#undef REGEN8
#undef TS

  // rowsum: lanes l and l^32 hold the two k-halves of row lm
  sumP += __shfl_xor(sumP, 32);
  if (lh == 0) rowsumP[(size_t)ks * NN + rA] = sumP;

  float* dst = part + (size_t)ks * NN * FOUT;
  const int rowb = r0 + wv * 32 + 4 * lh;
#pragma unroll
  for (int c = 0; c < 8; ++c) {
    const int col = c * 32 + lm;
#pragma unroll
    for (int reg = 0; reg < 16; ++reg) {
      int row = rowb + (reg & 3) + 8 * (reg >> 2);
      dst[(size_t)row * FOUT + col] = acc[c][reg];
    }
  }
}

// ---------------- K4: sum 8 K-partials + rowsums, normalize ---------------
__global__ __launch_bounds__(256) void k_fin(
    float* __restrict__ outp, const float* __restrict__ part,
    const float* __restrict__ rowsumP)
{
  const int idx4 = blockIdx.x * 256 + threadIdx.x;
  const size_t e = (size_t)idx4 * 4;
  const int i = (int)(e >> 8);
  float rs = 0.f;
#pragma unroll
  for (int p = 0; p < 8; ++p) rs += rowsumP[(size_t)p * NN + i];
  float4 o = {0.f, 0.f, 0.f, 0.f};
#pragma unroll
  for (int p = 0; p < 8; ++p) {
    float4 pv = *(const float4*)(part + (size_t)p * NN * FOUT + e);
    o.x += pv.x; o.y += pv.y; o.z += pv.z; o.w += pv.w;
  }
  float inv = 1.f / rs;
  o.x *= inv; o.y *= inv; o.z *= inv; o.w *= inv;
  *(float4*)(outp + e) = o;
}

extern "C" void kernel_launch(void* const* d_in, const int* in_sizes, int n_in,
                              void* d_out, int out_size, void* d_ws, size_t ws_size,
                              hipStream_t stream)
{
  const float* x  = (const float*)d_in[0];
  const int* adj  = (const int*)d_in[1];
  const float* Wm = (const float*)d_in[2];
  const float* aG = (const float*)d_in[3];
  float* outp = (float*)d_out;

  char* w = (char*)d_ws;
  unsigned short* hTt  = (unsigned short*)(w + 0);           // 4 MB (tiled)
  float* f1            = (float*)(w + 4194304);              // 32 KB
  float* f2            = (float*)(w + 4227072);              // 32 KB
  float* mhat          = (float*)(w + 4259840);              // 32 KB
  float* rowsumP       = (float*)(w + 4292608);              // 256 KB
  unsigned short* WtHi = (unsigned short*)(w + 4554752);     // 256 KB
  unsigned short* WtLo = (unsigned short*)(w + 4816896);     // 256 KB
  float* part          = (float*)(w + 5079040);              // 64 MB (8 slices)

  hipLaunchKernelGGL(k_prep,   dim3(32),    dim3(256),  0, stream, Wm, WtHi, WtLo);
  hipLaunchKernelGGL(k_gemm_h, dim3(256),   dim3(256),  0, stream, x, WtHi, WtLo, aG, hTt, f1, f2);
  hipLaunchKernelGGL(k_bound,  dim3(1),     dim3(1024), 0, stream, f1, f2, mhat);
  hipLaunchKernelGGL(k_spmm,   dim3(64, 8), dim3(256),  0, stream, hTt, adj, f1, f2, mhat, part, rowsumP);
  hipLaunchKernelGGL(k_fin,    dim3(2048),  dim3(256),  0, stream, outp, part, rowsumP);
}

// Round 14
// 151.153 us; speedup vs baseline: 1.1543x; 1.1543x over previous
//
#include <hip/hip_runtime.h>
#include <hip/hip_bf16.h>
#include <stdint.h>

#define NN 8192
#define FIN 512
#define FOUT 256
#define ALPHAV 0.2f
#define MASKF 9e-15f
#define L2E 1.44269504088896340736f

typedef __attribute__((ext_vector_type(8))) short bf16x8;
typedef __attribute__((ext_vector_type(16))) float f32x16;

static __device__ __forceinline__ float ex2(float x){
#if __has_builtin(__builtin_amdgcn_exp2f)
  return __builtin_amdgcn_exp2f(x);
#else
  return exp2f(x);
#endif
}
static __device__ __forceinline__ unsigned short f2bf(float f){
  __bf16 b = (__bf16)f;
  return __builtin_bit_cast(unsigned short, b);
}
static __device__ __forceinline__ float bf2f(unsigned short u){
  unsigned int v = ((unsigned int)u) << 16;
  return __builtin_bit_cast(float, v);
}

// ---------------- K0: W(512x256 f32) -> Wt hi/lo, step-tiled bf16 ---------
__global__ __launch_bounds__(256) void k_prep(
    const float* __restrict__ Wm, unsigned short* __restrict__ WtHi,
    unsigned short* __restrict__ WtLo)
{
  __shared__ float ls[16 * 256];
  const int t = threadIdx.x;
  const int S = blockIdx.x;          // kstep 0..31
  const int k0 = S * 16;
  {
    const int kk = t >> 4;
    const int n0 = (t & 15) * 16;
#pragma unroll
    for (int q = 0; q < 4; ++q) {
      float4 v = *(const float4*)(Wm + (size_t)(k0 + kk) * FOUT + n0 + q * 4);
      *(float4*)(&ls[kk * 256 + n0 + q * 4]) = v;
    }
  }
  __syncthreads();
  float v[16];
  unsigned short hh[16], ll[16];
#pragma unroll
  for (int kk = 0; kk < 16; ++kk) {
    v[kk] = ls[kk * 256 + t];
    hh[kk] = f2bf(v[kk]);
    ll[kk] = f2bf(v[kk] - bf2f(hh[kk]));
  }
  unsigned short* oh = WtHi + (size_t)S * 4096 + t * 8;
  unsigned short* ol = WtLo + (size_t)S * 4096 + t * 8;
#pragma unroll
  for (int g = 0; g < 2; ++g) {      // kg 0/1
    ushort4 a, b, c, d;
    a.x = hh[g*8+0]; a.y = hh[g*8+1]; a.z = hh[g*8+2]; a.w = hh[g*8+3];
    b.x = hh[g*8+4]; b.y = hh[g*8+5]; b.z = hh[g*8+6]; b.w = hh[g*8+7];
    c.x = ll[g*8+0]; c.y = ll[g*8+1]; c.z = ll[g*8+2]; c.w = ll[g*8+3];
    d.x = ll[g*8+4]; d.y = ll[g*8+5]; d.z = ll[g*8+6]; d.w = ll[g*8+7];
    *(ushort4*)(oh + g * 2048)     = a;
    *(ushort4*)(oh + g * 2048 + 4) = b;
    *(ushort4*)(ol + g * 2048)     = c;
    *(ushort4*)(ol + g * 2048 + 4) = d;
  }
}

// ---------------- K1: hTt = (x@W)^T via 32x32x16 MFMA, hi/lo split --------
// (unchanged from R12 — measured ~6 µs)
__global__ __launch_bounds__(256, 1) void k_gemm_h(
    const float* __restrict__ x, const unsigned short* __restrict__ WtHi,
    const unsigned short* __restrict__ WtLo, const float* __restrict__ aG,
    unsigned short* __restrict__ hTt, float* __restrict__ f1,
    float* __restrict__ f2)
{
  __shared__ __align__(16) unsigned short xhi[16384];
  __shared__ __align__(16) unsigned short xlo[16384];
  __shared__ __align__(16) unsigned short wsh[3][4096];
  __shared__ __align__(16) unsigned short wsl[3][4096];
  __shared__ __align__(16) float as2[512];
  __shared__ float f1red[4][32], f2red[4][32];

  const int t  = threadIdx.x;
  const int wv = t >> 6;
  const int l  = t & 63;
  const int lh = l >> 5;
  const int lm = l & 31;
  const int i0 = blockIdx.x * 32;

  if (t < 128) {
    float4 v = *(const float4*)(aG + t * 4);
    *(float4*)(&as2[t * 4]) = v;
  }
  {
    const int xi = t >> 3;
    const int kb = (t & 7) * 4;
    const float* xrow = x + (size_t)(i0 + xi) * FIN;
    const int kgb = (t & 7) >> 1;
    const int bo  = (t & 1) * 4;
#pragma unroll
    for (int q = 0; q < 16; ++q) {
      float4 v = *(const float4*)(xrow + kb + q * 32);
      ushort4 h4, l4;
      h4.x = f2bf(v.x); l4.x = f2bf(v.x - bf2f(h4.x));
      h4.y = f2bf(v.y); l4.y = f2bf(v.y - bf2f(h4.y));
      h4.z = f2bf(v.z); l4.z = f2bf(v.z - bf2f(h4.z));
      h4.w = f2bf(v.w); l4.w = f2bf(v.w - bf2f(h4.w));
      const int idx = (q * 4 + kgb) * 256 + xi * 8 + bo;
      *(ushort4*)(&xhi[idx]) = h4;
      *(ushort4*)(&xlo[idx]) = l4;
    }
  }

  f32x16 acc0, acc1;
#pragma unroll
  for (int e = 0; e < 16; ++e) { acc0[e] = 0.f; acc1[e] = 0.f; }

#define SB0 __builtin_amdgcn_sched_barrier(0)
#define WSTAGE(B, S)                                                          \
  do {                                                                        \
    const unsigned short* gh_ = WtHi + (size_t)(S) * 4096 + t * 8;            \
    const unsigned short* gl_ = WtLo + (size_t)(S) * 4096 + t * 8;            \
    __builtin_amdgcn_global_load_lds(                                         \
        (const __attribute__((address_space(1))) unsigned int*)gh_,           \
        (__attribute__((address_space(3))) unsigned int*)(&wsh[B][t * 8]), 16, 0, 0); \
    __builtin_amdgcn_global_load_lds(                                         \
        (const __attribute__((address_space(1))) unsigned int*)(gh_ + 2048),  \
        (__attribute__((address_space(3))) unsigned int*)(&wsh[B][2048 + t * 8]), 16, 0, 0); \
    __builtin_amdgcn_global_load_lds(                                         \
        (const __attribute__((address_space(1))) unsigned int*)gl_,           \
        (__attribute__((address_space(3))) unsigned int*)(&wsl[B][t * 8]), 16, 0, 0); \
    __builtin_amdgcn_global_load_lds(                                         \
        (const __attribute__((address_space(1))) unsigned int*)(gl_ + 2048),  \
        (__attribute__((address_space(3))) unsigned int*)(&wsl[B][2048 + t * 8]), 16, 0, 0); \
  } while (0)

#define GTS(S, BUF, DOISSUE, NBUF, VMC)                                       \
  do {                                                                        \
    asm volatile("s_waitcnt vmcnt(" #VMC ")" ::: "memory");                   \
    __builtin_amdgcn_s_barrier();                                             \
    SB0;                                                                      \
    if (DOISSUE) WSTAGE(NBUF, (S) + 2);                                       \
    SB0;                                                                      \
    const int kgb_ = ((S) * 2 + lh) * 512 + lm * 16;                          \
    bf16x8 bh_ = *(const bf16x8*)(((const char*)xhi) + kgb_);                 \
    bf16x8 bl_ = *(const bf16x8*)(((const char*)xlo) + kgb_);                 \
    const int na_ = lh * 4096 + (wv * 64 + lm) * 16;                          \
    bf16x8 ah0_ = *(const bf16x8*)(((const char*)&wsh[BUF][0]) + na_);        \
    bf16x8 al0_ = *(const bf16x8*)(((const char*)&wsl[BUF][0]) + na_);        \
    bf16x8 ah1_ = *(const bf16x8*)(((const char*)&wsh[BUF][0]) + na_ + 512);  \
    bf16x8 al1_ = *(const bf16x8*)(((const char*)&wsl[BUF][0]) + na_ + 512);  \
    acc0 = __builtin_amdgcn_mfma_f32_32x32x16_bf16(ah0_, bh_, acc0, 0, 0, 0); \
    acc1 = __builtin_amdgcn_mfma_f32_32x32x16_bf16(ah1_, bh_, acc1, 0, 0, 0); \
    acc0 = __builtin_amdgcn_mfma_f32_32x32x16_bf16(ah0_, bl_, acc0, 0, 0, 0); \
    acc1 = __builtin_amdgcn_mfma_f32_32x32x16_bf16(ah1_, bl_, acc1, 0, 0, 0); \
    acc0 = __builtin_amdgcn_mfma_f32_32x32x16_bf16(al0_, bh_, acc0, 0, 0, 0); \
    acc1 = __builtin_amdgcn_mfma_f32_32x32x16_bf16(al1_, bh_, acc1, 0, 0, 0); \
  } while (0)

  asm volatile("s_waitcnt vmcnt(0)" ::: "memory");
  SB0;
  WSTAGE(0, 0);
  SB0;
  WSTAGE(1, 1);
  asm volatile("s_waitcnt lgkmcnt(0)" ::: "memory");
  SB0;

#pragma unroll 1
  for (int p = 0; p < 10; ++p) {
    const int s0 = p * 3;
    GTS(s0 + 0, 0, 1, 2, 4);
    GTS(s0 + 1, 1, 1, 0, 4);
    GTS(s0 + 2, 2, 1, 1, 4);
  }
  GTS(30, 0, 0, 2, 4);
  GTS(31, 1, 0, 0, 0);
#undef SB0
#undef WSTAGE
#undef GTS

  float p1 = 0.f, p2 = 0.f;
#pragma unroll
  for (int reg = 0; reg < 16; ++reg) {
    const int nl = (reg & 3) + 8 * (reg >> 2) + 4 * lh;
    p1 += acc0[reg] * as2[wv * 64 + nl]       + acc1[reg] * as2[wv * 64 + 32 + nl];
    p2 += acc0[reg] * as2[256 + wv * 64 + nl] + acc1[reg] * as2[256 + wv * 64 + 32 + nl];
  }
  p1 += __shfl_xor(p1, 32);
  p2 += __shfl_xor(p2, 32);
  if (l < 32) { f1red[wv][l] = p1; f2red[wv][l] = p2; }
  __syncthreads();
  if (t < 32) {
    f1[i0 + t] = f1red[0][t] + f1red[1][t] + f1red[2][t] + f1red[3][t];
    f2[i0 + t] = f2red[0][t] + f2red[1][t] + f2red[2][t] + f2red[3][t];
  }

  const size_t hb = (size_t)(i0 >> 5) * 8192 + (size_t)(lm >> 3) * 2048 + (lm & 7);
#pragma unroll
  for (int reg = 0; reg < 16; ++reg) {
    const int nl = (reg & 3) + 8 * (reg >> 2) + 4 * lh;
    hTt[hb + (size_t)(wv * 64 + nl) * 8]      = f2bf(acc0[reg]);
    hTt[hb + (size_t)(wv * 64 + 32 + nl) * 8] = f2bf(acc1[reg]);
  }
}

// ---------------- K2: row-max UPPER BOUND m̂_i = lrelu(f1_i + max f2) ------
__global__ __launch_bounds__(1024) void k_bound(
    const float* __restrict__ f1, const float* __restrict__ f2,
    float* __restrict__ mhat)
{
  __shared__ float red[16];
  const int t = threadIdx.x;
  float m = -3.0e38f;
#pragma unroll
  for (int k = 0; k < 8; ++k) m = fmaxf(m, f2[t + k * 1024]);
#pragma unroll
  for (int off = 32; off > 0; off >>= 1) m = fmaxf(m, __shfl_xor(m, off));
  if ((t & 63) == 0) red[t >> 6] = m;
  __syncthreads();
  float fm = red[0];
#pragma unroll
  for (int w = 1; w < 16; ++w) fm = fmaxf(fm, red[w]);
#pragma unroll
  for (int k = 0; k < 8; ++k) {
    int i = t + k * 1024;
    float s = f1[i] + fm;
    mhat[i] = fmaxf(fmaxf(s, ALPHAV * s), MASKF);
  }
}

// ---------------- K3: fused adj->bitmask prologue + pipelined MFMA loop ---
// BM=64, grid (128,8) = 1024 blocks = 2 generations on 512 slots: gen-2's
// HBM-bound prologue overlaps gen-1's compute. Waves: 2(wr)x2(wc); P-regen
// duplicated x2 (acceptable). afr PIPELINED one step ahead (E/O named sets):
// per-step critical path = barrier -> 8 ds_read -> 8 MFMA; REGEN(jt+1)
// co-issues on the VALU pipe. Coalesced prologue (R12's proven pattern),
// counted vmcnt(4), 3 LDS staging buffers.
__global__ __launch_bounds__(256, 2) void k_spmm(
    const unsigned short* __restrict__ hTt,
    const int* __restrict__ adj,
    const float* __restrict__ f1, const float* __restrict__ f2,
    const float* __restrict__ mhat,
    float* __restrict__ part, float* __restrict__ rowsumP)
{
  __shared__ __align__(16) unsigned short hbuf[3 * 8192]; // 3 x 16 KB
  __shared__ __align__(16) unsigned int mskL[32 * 66];    // [jt][row64]+pad
  __shared__ __align__(16) float f2s[1024];               // pre-scaled by L2E
  const int t  = threadIdx.x;
  const int wv = t >> 6;
  const int l  = t & 63;
  const int lh = l >> 5;           // k-half of lane
  const int lm = l & 31;           // row (A) / col (B) within 32
  const int wr = wv >> 1;          // row group (32 rows)
  const int wc = wv & 1;           // col half (128 cols)
  const int bx = blockIdx.x;
  const int ks = blockIdx.y;
  const int r0 = bx * 64;
  const int lh8 = lh * 8;

  const int rA = r0 + wr * 32 + lm;
  const float nmA   = -mhat[rA] * L2E;
  const float base0 = fmaf(f1[rA], L2E, nmA);
  const float c20   = nmA * (1.f - ALPHAV);
  const float mc0   = fmaf(MASKF, L2E, nmA);

  // f2 slice -> LDS (pre-scaled)
  {
    float4 v = *(const float4*)(f2 + ks * 1024 + t * 4);
    v.x *= L2E; v.y *= L2E; v.z *= L2E; v.w *= L2E;
    *(float4*)(&f2s[t * 4]) = v;
  }

  // ---- prologue: adj(64 rows x 1024 j) -> mskL, coalesced row-chunks ----
  // pass p: rows p*8..p*8+7; thread reads 128 B contiguous of one row.
  {
    const int jt = t & 31;
    const int r8 = t >> 5;
    const int* gp = adj + (size_t)(r0 + r8) * NN + ks * 1024 + jt * 32;
#pragma unroll 2
    for (int p = 0; p < 8; ++p) {
      const int* rp = gp + (size_t)p * 8 * NN;
      int4 v[8];
#pragma unroll
      for (int c = 0; c < 8; ++c) v[c] = *(const int4*)(rp + c * 4);
      unsigned int m = 0;
#pragma unroll
      for (int c = 0; c < 8; ++c) {
        m |= (v[c].x > 0 ? 1u : 0u) << (c * 4 + 0);
        m |= (v[c].y > 0 ? 1u : 0u) << (c * 4 + 1);
        m |= (v[c].z > 0 ? 1u : 0u) << (c * 4 + 2);
        m |= (v[c].w > 0 ? 1u : 0u) << (c * 4 + 3);
      }
      mskL[jt * 66 + p * 8 + r8] = m;
    }
  }
  // mask + f2s visible to all waves before REGEN(0)
  asm volatile("s_waitcnt lgkmcnt(0)" ::: "memory");
  __builtin_amdgcn_s_barrier();
  __builtin_amdgcn_sched_barrier(0);

  f32x16 acc[4];
#pragma unroll
  for (int c = 0; c < 4; ++c)
#pragma unroll
    for (int e = 0; e < 16; ++e) acc[c][e] = 0.f;
  float sumP = 0.f;

  const char* cbase = (const char*)hbuf;
  const int mrow = wr * 32 + lm;

#define SB0 __builtin_amdgcn_sched_barrier(0)
#define STAGE(BUFI, JT)                                                       \
  do {                                                                        \
    const unsigned short* gp_ = hTt + (size_t)ks * 32 * 8192                  \
                                + (size_t)(JT) * 8192 + t * 8;                \
    char* lp_ = ((char*)hbuf) + (BUFI) * 16384 + t * 16;                      \
    _Pragma("unroll")                                                         \
    for (int c = 0; c < 4; ++c) {                                             \
      __builtin_amdgcn_global_load_lds(                                       \
          (const __attribute__((address_space(1))) unsigned int*)(gp_ + c * 2048), \
          (__attribute__((address_space(3))) unsigned int*)(lp_ + c * 4096),  \
          16, 0, 0);                                                          \
    }                                                                         \
  } while (0)

#define REGEN8(AFR, MB, FB)                                                   \
  do {                                                                        \
    float4 fx_ = *(const float4*)(&f2s[FB]);                                  \
    float4 fy_ = *(const float4*)(&f2s[(FB) + 4]);                            \
    float fv_[8] = {fx_.x, fx_.y, fx_.z, fx_.w, fy_.x, fy_.y, fy_.z, fy_.w};  \
    _Pragma("unroll")                                                         \
    for (int b = 0; b < 8; ++b) {                                             \
      float u_ = base0 + fv_[b];                                              \
      float w_ = fmaxf(u_, fmaf(ALPHAV, u_, c20));                            \
      w_ = (((MB) >> b) & 1u) ? w_ : mc0;                                     \
      float p_ = ex2(w_);                                                     \
      sumP += p_;                                                             \
      AFR[b] = (short)f2bf(p_);                                               \
    }                                                                         \
  } while (0)

#define REGEN_STEP(A0, A1, JT)                                                \
  do {                                                                        \
    const unsigned int m_ = mskL[(JT) * 66 + mrow];                           \
    REGEN8(A0, m_ >> lh8,        (JT) * 32 + lh8);                            \
    REGEN8(A1, m_ >> (16 + lh8), (JT) * 32 + 16 + lh8);                       \
  } while (0)

// step jt: MFMA consumes AFRC (ready); REGEN(jt+1) fills AFRN (no SB0
// between them -> VALU co-issues with LDS/MFMA).
#define TS(JT, BUF, NBUF, C0, C1, N0, N1, DOREGEN, DOSTAGE, VMC)              \
  do {                                                                        \
    asm volatile("s_waitcnt vmcnt(" #VMC ")" ::: "memory");                   \
    __builtin_amdgcn_s_barrier();                                             \
    SB0;                                                                      \
    if (DOSTAGE) STAGE(NBUF, (JT) + 2);                                       \
    SB0;                                                                      \
    if (DOREGEN) REGEN_STEP(N0, N1, (JT) + 1);                                \
    const char* lb_ = cbase + (BUF) * 16384;                                  \
    const int g0_ = lh * 4096;                                                \
    const int g1_ = (2 + lh) * 4096;                                          \
    const int cb_ = (wc * 128 + lm) * 16;                                     \
    _Pragma("unroll")                                                         \
    for (int c = 0; c < 4; ++c) {                                             \
      bf16x8 b0_ = *(const bf16x8*)(lb_ + g0_ + c * 512 + cb_);               \
      acc[c] = __builtin_amdgcn_mfma_f32_32x32x16_bf16(C0, b0_, acc[c], 0, 0, 0); \
      bf16x8 b1_ = *(const bf16x8*)(lb_ + g1_ + c * 512 + cb_);               \
      acc[c] = __builtin_amdgcn_mfma_f32_32x32x16_bf16(C1, b1_, acc[c], 0, 0, 0); \
    }                                                                         \
  } while (0)

  bf16x8 aE0, aE1, aO0, aO1;
  REGEN_STEP(aE0, aE1, 0);           // afr for step 0 (E set)
  SB0;
  // counted stream starts here (prologue adj loads all drained above)
  STAGE(0, 0);
  SB0;
  STAGE(1, 1);
  SB0;

#pragma unroll 1
  for (int p = 0; p < 5; ++p) {
    const int s0 = p * 6;
    TS(s0 + 0, 0, 2, aE0, aE1, aO0, aO1, 1, 1, 4);
    TS(s0 + 1, 1, 0, aO0, aO1, aE0, aE1, 1, 1, 4);
    TS(s0 + 2, 2, 1, aE0, aE1, aO0, aO1, 1, 1, 4);
    TS(s0 + 3, 0, 2, aO0, aO1, aE0, aE1, 1, 1, 4);
    TS(s0 + 4, 1, 0, aE0, aE1, aO0, aO1, 1, 1, 4);
    TS(s0 + 5, 2, 1, aO0, aO1, aE0, aE1, 1, 1, 4);
  }
  TS(30, 0, 2, aE0, aE1, aO0, aO1, 1, 0, 4);   // REGEN(31), no stage
  TS(31, 1, 0, aO0, aO1, aE0, aE1, 0, 0, 0);

#undef SB0
#undef STAGE
#undef REGEN8
#undef REGEN_STEP
#undef TS

  // rowsum: lanes l and l^32 hold the two k-halves of row lm; wc dup -> wc0
  sumP += __shfl_xor(sumP, 32);
  if (lh == 0 && wc == 0) rowsumP[(size_t)ks * NN + rA] = sumP;

  // C-write: col = wc*128 + c*32 + lm; row = r0+wr*32+4*lh+(reg&3)+8*(reg>>2)
  float* dst = part + (size_t)ks * NN * FOUT;
  const int rowb = r0 + wr * 32 + 4 * lh;
#pragma unroll
  for (int c = 0; c < 4; ++c) {
    const int col = wc * 128 + c * 32 + lm;
#pragma unroll
    for (int reg = 0; reg < 16; ++reg) {
      int row = rowb + (reg & 3) + 8 * (reg >> 2);
      dst[(size_t)row * FOUT + col] = acc[c][reg];
    }
  }
}

// ---------------- K4: sum 8 K-partials + rowsums, normalize ---------------
__global__ __launch_bounds__(256) void k_fin(
    float* __restrict__ outp, const float* __restrict__ part,
    const float* __restrict__ rowsumP)
{
  const int idx4 = blockIdx.x * 256 + threadIdx.x;
  const size_t e = (size_t)idx4 * 4;
  const int i = (int)(e >> 8);
  float rs = 0.f;
#pragma unroll
  for (int p = 0; p < 8; ++p) rs += rowsumP[(size_t)p * NN + i];
  float4 o = {0.f, 0.f, 0.f, 0.f};
#pragma unroll
  for (int p = 0; p < 8; ++p) {
    float4 pv = *(const float4*)(part + (size_t)p * NN * FOUT + e);
    o.x += pv.x; o.y += pv.y; o.z += pv.z; o.w += pv.w;
  }
  float inv = 1.f / rs;
  o.x *= inv; o.y *= inv; o.z *= inv; o.w *= inv;
  *(float4*)(outp + e) = o;
}

extern "C" void kernel_launch(void* const* d_in, const int* in_sizes, int n_in,
                              void* d_out, int out_size, void* d_ws, size_t ws_size,
                              hipStream_t stream)
{
  const float* x  = (const float*)d_in[0];
  const int* adj  = (const int*)d_in[1];
  const float* Wm = (const float*)d_in[2];
  const float* aG = (const float*)d_in[3];
  float* outp = (float*)d_out;

  char* w = (char*)d_ws;
  unsigned short* hTt  = (unsigned short*)(w + 0);           // 4 MB (tiled)
  float* f1            = (float*)(w + 4194304);              // 32 KB
  float* f2            = (float*)(w + 4227072);              // 32 KB
  float* mhat          = (float*)(w + 4259840);              // 32 KB
  float* rowsumP       = (float*)(w + 4292608);              // 256 KB
  unsigned short* WtHi = (unsigned short*)(w + 4554752);     // 256 KB
  unsigned short* WtLo = (unsigned short*)(w + 4816896);     // 256 KB
  float* part          = (float*)(w + 5079040);              // 64 MB (8 slices)

  hipLaunchKernelGGL(k_prep,   dim3(32),     dim3(256),  0, stream, Wm, WtHi, WtLo);
  hipLaunchKernelGGL(k_gemm_h, dim3(256),    dim3(256),  0, stream, x, WtHi, WtLo, aG, hTt, f1, f2);
  hipLaunchKernelGGL(k_bound,  dim3(1),      dim3(1024), 0, stream, f1, f2, mhat);
  hipLaunchKernelGGL(k_spmm,   dim3(128, 8), dim3(256),  0, stream, hTt, adj, f1, f2, mhat, part, rowsumP);
  hipLaunchKernelGGL(k_fin,    dim3(2048),   dim3(256),  0, stream, outp, part, rowsumP);
}

// Round 15
// 127.982 us; speedup vs baseline: 1.3633x; 1.1811x over previous
//
#include <hip/hip_runtime.h>
#include <hip/hip_bf16.h>
#include <stdint.h>

#define NN 8192
#define FIN 512
#define FOUT 256
#define ALPHAV 0.2f
#define MASKF 9e-15f
#define L2E 1.44269504088896340736f

typedef __attribute__((ext_vector_type(8))) short bf16x8;
typedef __attribute__((ext_vector_type(16))) float f32x16;

static __device__ __forceinline__ float ex2(float x){
#if __has_builtin(__builtin_amdgcn_exp2f)
  return __builtin_amdgcn_exp2f(x);
#else
  return exp2f(x);
#endif
}
static __device__ __forceinline__ unsigned short f2bf(float f){
  __bf16 b = (__bf16)f;
  return __builtin_bit_cast(unsigned short, b);
}
static __device__ __forceinline__ float bf2f(unsigned short u){
  unsigned int v = ((unsigned int)u) << 16;
  return __builtin_bit_cast(float, v);
}

// ---------------- K0: W(512x256 f32) -> Wt hi/lo, step-tiled bf16 ---------
__global__ __launch_bounds__(256) void k_prep(
    const float* __restrict__ Wm, unsigned short* __restrict__ WtHi,
    unsigned short* __restrict__ WtLo)
{
  __shared__ float ls[16 * 256];
  const int t = threadIdx.x;
  const int S = blockIdx.x;          // kstep 0..31
  const int k0 = S * 16;
  {
    const int kk = t >> 4;
    const int n0 = (t & 15) * 16;
#pragma unroll
    for (int q = 0; q < 4; ++q) {
      float4 v = *(const float4*)(Wm + (size_t)(k0 + kk) * FOUT + n0 + q * 4);
      *(float4*)(&ls[kk * 256 + n0 + q * 4]) = v;
    }
  }
  __syncthreads();
  float v[16];
  unsigned short hh[16], ll[16];
#pragma unroll
  for (int kk = 0; kk < 16; ++kk) {
    v[kk] = ls[kk * 256 + t];
    hh[kk] = f2bf(v[kk]);
    ll[kk] = f2bf(v[kk] - bf2f(hh[kk]));
  }
  unsigned short* oh = WtHi + (size_t)S * 4096 + t * 8;
  unsigned short* ol = WtLo + (size_t)S * 4096 + t * 8;
#pragma unroll
  for (int g = 0; g < 2; ++g) {      // kg 0/1
    ushort4 a, b, c, d;
    a.x = hh[g*8+0]; a.y = hh[g*8+1]; a.z = hh[g*8+2]; a.w = hh[g*8+3];
    b.x = hh[g*8+4]; b.y = hh[g*8+5]; b.z = hh[g*8+6]; b.w = hh[g*8+7];
    c.x = ll[g*8+0]; c.y = ll[g*8+1]; c.z = ll[g*8+2]; c.w = ll[g*8+3];
    d.x = ll[g*8+4]; d.y = ll[g*8+5]; d.z = ll[g*8+6]; d.w = ll[g*8+7];
    *(ushort4*)(oh + g * 2048)     = a;
    *(ushort4*)(oh + g * 2048 + 4) = b;
    *(ushort4*)(ol + g * 2048)     = c;
    *(ushort4*)(ol + g * 2048 + 4) = d;
  }
}

// ---------------- K1: hTt = (x@W)^T via 32x32x16 MFMA, hi/lo split --------
// (unchanged — measured ~6 µs)
__global__ __launch_bounds__(256, 1) void k_gemm_h(
    const float* __restrict__ x, const unsigned short* __restrict__ WtHi,
    const unsigned short* __restrict__ WtLo, const float* __restrict__ aG,
    unsigned short* __restrict__ hTt, float* __restrict__ f1,
    float* __restrict__ f2)
{
  __shared__ __align__(16) unsigned short xhi[16384];
  __shared__ __align__(16) unsigned short xlo[16384];
  __shared__ __align__(16) unsigned short wsh[3][4096];
  __shared__ __align__(16) unsigned short wsl[3][4096];
  __shared__ __align__(16) float as2[512];
  __shared__ float f1red[4][32], f2red[4][32];

  const int t  = threadIdx.x;
  const int wv = t >> 6;
  const int l  = t & 63;
  const int lh = l >> 5;
  const int lm = l & 31;
  const int i0 = blockIdx.x * 32;

  if (t < 128) {
    float4 v = *(const float4*)(aG + t * 4);
    *(float4*)(&as2[t * 4]) = v;
  }
  {
    const int xi = t >> 3;
    const int kb = (t & 7) * 4;
    const float* xrow = x + (size_t)(i0 + xi) * FIN;
    const int kgb = (t & 7) >> 1;
    const int bo  = (t & 1) * 4;
#pragma unroll
    for (int q = 0; q < 16; ++q) {
      float4 v = *(const float4*)(xrow + kb + q * 32);
      ushort4 h4, l4;
      h4.x = f2bf(v.x); l4.x = f2bf(v.x - bf2f(h4.x));
      h4.y = f2bf(v.y); l4.y = f2bf(v.y - bf2f(h4.y));
      h4.z = f2bf(v.z); l4.z = f2bf(v.z - bf2f(h4.z));
      h4.w = f2bf(v.w); l4.w = f2bf(v.w - bf2f(h4.w));
      const int idx = (q * 4 + kgb) * 256 + xi * 8 + bo;
      *(ushort4*)(&xhi[idx]) = h4;
      *(ushort4*)(&xlo[idx]) = l4;
    }
  }

  f32x16 acc0, acc1;
#pragma unroll
  for (int e = 0; e < 16; ++e) { acc0[e] = 0.f; acc1[e] = 0.f; }

#define SB0 __builtin_amdgcn_sched_barrier(0)
#define WSTAGE(B, S)                                                          \
  do {                                                                        \
    const unsigned short* gh_ = WtHi + (size_t)(S) * 4096 + t * 8;            \
    const unsigned short* gl_ = WtLo + (size_t)(S) * 4096 + t * 8;            \
    __builtin_amdgcn_global_load_lds(                                         \
        (const __attribute__((address_space(1))) unsigned int*)gh_,           \
        (__attribute__((address_space(3))) unsigned int*)(&wsh[B][t * 8]), 16, 0, 0); \
    __builtin_amdgcn_global_load_lds(                                         \
        (const __attribute__((address_space(1))) unsigned int*)(gh_ + 2048),  \
        (__attribute__((address_space(3))) unsigned int*)(&wsh[B][2048 + t * 8]), 16, 0, 0); \
    __builtin_amdgcn_global_load_lds(                                         \
        (const __attribute__((address_space(1))) unsigned int*)gl_,           \
        (__attribute__((address_space(3))) unsigned int*)(&wsl[B][t * 8]), 16, 0, 0); \
    __builtin_amdgcn_global_load_lds(                                         \
        (const __attribute__((address_space(1))) unsigned int*)(gl_ + 2048),  \
        (__attribute__((address_space(3))) unsigned int*)(&wsl[B][2048 + t * 8]), 16, 0, 0); \
  } while (0)

#define GTS(S, BUF, DOISSUE, NBUF, VMC)                                       \
  do {                                                                        \
    asm volatile("s_waitcnt vmcnt(" #VMC ")" ::: "memory");                   \
    __builtin_amdgcn_s_barrier();                                             \
    SB0;                                                                      \
    if (DOISSUE) WSTAGE(NBUF, (S) + 2);                                       \
    SB0;                                                                      \
    const int kgb_ = ((S) * 2 + lh) * 512 + lm * 16;                          \
    bf16x8 bh_ = *(const bf16x8*)(((const char*)xhi) + kgb_);                 \
    bf16x8 bl_ = *(const bf16x8*)(((const char*)xlo) + kgb_);                 \
    const int na_ = lh * 4096 + (wv * 64 + lm) * 16;                          \
    bf16x8 ah0_ = *(const bf16x8*)(((const char*)&wsh[BUF][0]) + na_);        \
    bf16x8 al0_ = *(const bf16x8*)(((const char*)&wsl[BUF][0]) + na_);        \
    bf16x8 ah1_ = *(const bf16x8*)(((const char*)&wsh[BUF][0]) + na_ + 512);  \
    bf16x8 al1_ = *(const bf16x8*)(((const char*)&wsl[BUF][0]) + na_ + 512);  \
    acc0 = __builtin_amdgcn_mfma_f32_32x32x16_bf16(ah0_, bh_, acc0, 0, 0, 0); \
    acc1 = __builtin_amdgcn_mfma_f32_32x32x16_bf16(ah1_, bh_, acc1, 0, 0, 0); \
    acc0 = __builtin_amdgcn_mfma_f32_32x32x16_bf16(ah0_, bl_, acc0, 0, 0, 0); \
    acc1 = __builtin_amdgcn_mfma_f32_32x32x16_bf16(ah1_, bl_, acc1, 0, 0, 0); \
    acc0 = __builtin_amdgcn_mfma_f32_32x32x16_bf16(al0_, bh_, acc0, 0, 0, 0); \
    acc1 = __builtin_amdgcn_mfma_f32_32x32x16_bf16(al1_, bh_, acc1, 0, 0, 0); \
  } while (0)

  asm volatile("s_waitcnt vmcnt(0)" ::: "memory");
  SB0;
  WSTAGE(0, 0);
  SB0;
  WSTAGE(1, 1);
  asm volatile("s_waitcnt lgkmcnt(0)" ::: "memory");
  SB0;

#pragma unroll 1
  for (int p = 0; p < 10; ++p) {
    const int s0 = p * 3;
    GTS(s0 + 0, 0, 1, 2, 4);
    GTS(s0 + 1, 1, 1, 0, 4);
    GTS(s0 + 2, 2, 1, 1, 4);
  }
  GTS(30, 0, 0, 2, 4);
  GTS(31, 1, 0, 0, 0);
#undef SB0
#undef WSTAGE
#undef GTS

  float p1 = 0.f, p2 = 0.f;
#pragma unroll
  for (int reg = 0; reg < 16; ++reg) {
    const int nl = (reg & 3) + 8 * (reg >> 2) + 4 * lh;
    p1 += acc0[reg] * as2[wv * 64 + nl]       + acc1[reg] * as2[wv * 64 + 32 + nl];
    p2 += acc0[reg] * as2[256 + wv * 64 + nl] + acc1[reg] * as2[256 + wv * 64 + 32 + nl];
  }
  p1 += __shfl_xor(p1, 32);
  p2 += __shfl_xor(p2, 32);
  if (l < 32) { f1red[wv][l] = p1; f2red[wv][l] = p2; }
  __syncthreads();
  if (t < 32) {
    f1[i0 + t] = f1red[0][t] + f1red[1][t] + f1red[2][t] + f1red[3][t];
    f2[i0 + t] = f2red[0][t] + f2red[1][t] + f2red[2][t] + f2red[3][t];
  }

  const size_t hb = (size_t)(i0 >> 5) * 8192 + (size_t)(lm >> 3) * 2048 + (lm & 7);
#pragma unroll
  for (int reg = 0; reg < 16; ++reg) {
    const int nl = (reg & 3) + 8 * (reg >> 2) + 4 * lh;
    hTt[hb + (size_t)(wv * 64 + nl) * 8]      = f2bf(acc0[reg]);
    hTt[hb + (size_t)(wv * 64 + 32 + nl) * 8] = f2bf(acc1[reg]);
  }
}

// ---------------- K2: row-max UPPER BOUND m̂_i = lrelu(f1_i + max f2) ------
__global__ __launch_bounds__(1024) void k_bound(
    const float* __restrict__ f1, const float* __restrict__ f2,
    float* __restrict__ mhat)
{
  __shared__ float red[16];
  const int t = threadIdx.x;
  float m = -3.0e38f;
#pragma unroll
  for (int k = 0; k < 8; ++k) m = fmaxf(m, f2[t + k * 1024]);
#pragma unroll
  for (int off = 32; off > 0; off >>= 1) m = fmaxf(m, __shfl_xor(m, off));
  if ((t & 63) == 0) red[t >> 6] = m;
  __syncthreads();
  float fm = red[0];
#pragma unroll
  for (int w = 1; w < 16; ++w) fm = fmaxf(fm, red[w]);
#pragma unroll
  for (int k = 0; k < 8; ++k) {
    int i = t + k * 1024;
    float s = f1[i] + fm;
    mhat[i] = fmaxf(fmaxf(s, ALPHAV * s), MASKF);
  }
}

// ---------------- K3: adj streamed (COALESCED passes) through MFMA loop ---
// R12 geometry: BM=128, 4 waves x full 256 cols, 3 hbuf, in-step REGEN.
// Masks double-buffered per 8-step chunk (mskD[2][8][128], 8KB): prologue
// converts chunk 0 only (128KB adj); loop steps 0-3 of chunk c each load
// one coalesced pass (8 int4/thread) of chunk c+1, converted next step.
// Hand-counted vmcnt per step: [4,12,20,20,20,12,4,4] x3, then [4..4,0].
// Partials stored bf16 (halves part traffic).
__global__ __launch_bounds__(256, 2) void k_spmm(
    const unsigned short* __restrict__ hTt,
    const int* __restrict__ adj,
    const float* __restrict__ f1, const float* __restrict__ f2,
    const float* __restrict__ mhat,
    unsigned short* __restrict__ partB, float* __restrict__ rowsumP)
{
  __shared__ __align__(16) unsigned short hbuf[3 * 8192]; // 48 KB
  __shared__ __align__(16) unsigned int mskD[2][8][128];  // 8 KB
  __shared__ __align__(16) float f2s[1024];               // 4 KB
  const int t  = threadIdx.x;
  const int wv = t >> 6;
  const int l  = t & 63;
  const int lh = l >> 5;
  const int lm = l & 31;
  const int bx = blockIdx.x;
  const int ks = blockIdx.y;
  const int r0 = bx * 128;
  const int lh8 = lh * 8;
  const int arow = t >> 3;   // 0..31 row within pass
  const int awrd = t & 7;    // word 0..7 (32 j each)

  const int rA = r0 + wv * 32 + lm;
  const float nmA   = -mhat[rA] * L2E;
  const float base0 = fmaf(f1[rA], L2E, nmA);
  const float c20   = nmA * (1.f - ALPHAV);
  const float mc0   = fmaf(MASKF, L2E, nmA);

  {
    float4 v = *(const float4*)(f2 + ks * 1024 + t * 4);
    v.x *= L2E; v.y *= L2E; v.z *= L2E; v.w *= L2E;
    *(float4*)(&f2s[t * 4]) = v;
  }

  int4 g0, g1, g2, g3, g4, g5, g6, g7;   // one adj pass in flight

#define SB0 __builtin_amdgcn_sched_barrier(0)
#define ADJP(P, CN)                                                           \
  do {                                                                        \
    const int* ap_ = adj + (size_t)(r0 + (P) * 32 + arow) * NN                \
                     + ks * 1024 + (CN) * 256 + awrd * 32;                    \
    g0 = ((const int4*)ap_)[0]; g1 = ((const int4*)ap_)[1];                   \
    g2 = ((const int4*)ap_)[2]; g3 = ((const int4*)ap_)[3];                   \
    g4 = ((const int4*)ap_)[4]; g5 = ((const int4*)ap_)[5];                   \
    g6 = ((const int4*)ap_)[6]; g7 = ((const int4*)ap_)[7];                   \
  } while (0)

#define CONVP(P, PAR)                                                         \
  do {                                                                        \
    unsigned int m_ = 0;                                                      \
    m_ |= (g0.x>0?1u:0u)<<0;  m_ |= (g0.y>0?1u:0u)<<1;                        \
    m_ |= (g0.z>0?1u:0u)<<2;  m_ |= (g0.w>0?1u:0u)<<3;                        \
    m_ |= (g1.x>0?1u:0u)<<4;  m_ |= (g1.y>0?1u:0u)<<5;                        \
    m_ |= (g1.z>0?1u:0u)<<6;  m_ |= (g1.w>0?1u:0u)<<7;                        \
    m_ |= (g2.x>0?1u:0u)<<8;  m_ |= (g2.y>0?1u:0u)<<9;                        \
    m_ |= (g2.z>0?1u:0u)<<10; m_ |= (g2.w>0?1u:0u)<<11;                       \
    m_ |= (g3.x>0?1u:0u)<<12; m_ |= (g3.y>0?1u:0u)<<13;                       \
    m_ |= (g3.z>0?1u:0u)<<14; m_ |= (g3.w>0?1u:0u)<<15;                       \
    m_ |= (g4.x>0?1u:0u)<<16; m_ |= (g4.y>0?1u:0u)<<17;                       \
    m_ |= (g4.z>0?1u:0u)<<18; m_ |= (g4.w>0?1u:0u)<<19;                       \
    m_ |= (g5.x>0?1u:0u)<<20; m_ |= (g5.y>0?1u:0u)<<21;                       \
    m_ |= (g5.z>0?1u:0u)<<22; m_ |= (g5.w>0?1u:0u)<<23;                       \
    m_ |= (g6.x>0?1u:0u)<<24; m_ |= (g6.y>0?1u:0u)<<25;                       \
    m_ |= (g6.z>0?1u:0u)<<26; m_ |= (g6.w>0?1u:0u)<<27;                       \
    m_ |= (g7.x>0?1u:0u)<<28; m_ |= (g7.y>0?1u:0u)<<29;                       \
    m_ |= (g7.z>0?1u:0u)<<30; m_ |= (g7.w>0?1u:0u)<<31;                       \
    mskD[PAR][awrd][(P) * 32 + arow] = m_;                                    \
  } while (0)

#define STAGE(BUFI, JT)                                                       \
  do {                                                                        \
    const unsigned short* gp_ = hTt + (size_t)ks * 32 * 8192                  \
                                + (size_t)(JT) * 8192 + t * 8;                \
    char* lp_ = ((char*)hbuf) + (BUFI) * 16384 + t * 16;                      \
    _Pragma("unroll")                                                         \
    for (int c = 0; c < 4; ++c) {                                             \
      __builtin_amdgcn_global_load_lds(                                       \
          (const __attribute__((address_space(1))) unsigned int*)(gp_ + c * 2048), \
          (__attribute__((address_space(3))) unsigned int*)(lp_ + c * 4096),  \
          16, 0, 0);                                                          \
    }                                                                         \
  } while (0)

#define REGEN8(AFR, MB, FB)                                                   \
  do {                                                                        \
    float4 fx_ = *(const float4*)(&f2s[FB]);                                  \
    float4 fy_ = *(const float4*)(&f2s[(FB) + 4]);                            \
    float fv_[8] = {fx_.x, fx_.y, fx_.z, fx_.w, fy_.x, fy_.y, fy_.z, fy_.w};  \
    _Pragma("unroll")                                                         \
    for (int b = 0; b < 8; ++b) {                                             \
      float u_ = base0 + fv_[b];                                              \
      float w_ = fmaxf(u_, fmaf(ALPHAV, u_, c20));                            \
      w_ = (((MB) >> b) & 1u) ? w_ : mc0;                                     \
      float p_ = ex2(w_);                                                     \
      sumP += p_;                                                             \
      AFR[b] = (short)f2bf(p_);                                               \
    }                                                                         \
  } while (0)

// One 32-j step. DOCONV converts pass CP into parity CPAR; DOADJ loads
// pass AP of chunk ACN. Issue order (fixed by SB0): CONV ds_write, STAGE
// (4 vmem), ADJ (8 vmem) -> counted stream per step = 4 or 12 ops.
#define STEP(JT, BUF, NBUF, DOSTAGE, VMC, DOCONV, CP, CPAR, DOADJ, AP, ACN)   \
  do {                                                                        \
    asm volatile("s_waitcnt vmcnt(" #VMC ")" ::: "memory");                   \
    __builtin_amdgcn_s_barrier();                                             \
    SB0;                                                                      \
    if (DOCONV) CONVP(CP, CPAR);                                              \
    if (DOSTAGE) STAGE(NBUF, (JT) + 2);                                       \
    SB0;                                                                      \
    if (DOADJ) ADJP(AP, ACN);                                                 \
    SB0;                                                                      \
    const unsigned int m_ = mskD[((JT) >> 3) & 1][(JT) & 7][mrow];            \
    bf16x8 afr0_, afr1_;                                                      \
    REGEN8(afr0_, m_ >> lh8,        (JT) * 32 + lh8);                         \
    REGEN8(afr1_, m_ >> (16 + lh8), (JT) * 32 + 16 + lh8);                    \
    SB0;                                                                      \
    const char* lb_ = cbase + (BUF) * 16384;                                  \
    const int gg0_ = lh * 4096;                                               \
    const int gg1_ = (2 + lh) * 4096;                                         \
    const int cb_ = lm * 16;                                                  \
    _Pragma("unroll")                                                         \
    for (int c = 0; c < 8; ++c) {                                             \
      bf16x8 b0_ = *(const bf16x8*)(lb_ + gg0_ + c * 512 + cb_);              \
      acc[c] = __builtin_amdgcn_mfma_f32_32x32x16_bf16(afr0_, b0_, acc[c], 0, 0, 0); \
      bf16x8 b1_ = *(const bf16x8*)(lb_ + gg1_ + c * 512 + cb_);              \
      acc[c] = __builtin_amdgcn_mfma_f32_32x32x16_bf16(afr1_, b1_, acc[c], 0, 0, 0); \
    }                                                                         \
  } while (0)

  // ---- prologue: chunk 0 masks (4 coalesced passes, 128 KB adj) ----------
#pragma unroll
  for (int p = 0; p < 4; ++p) {
    ADJP(p, 0);
    CONVP(p, 0);
  }
  asm volatile("s_waitcnt lgkmcnt(0)" ::: "memory");  // mskD[0] + f2s writes
  __builtin_amdgcn_s_barrier();
  SB0;

  f32x16 acc[8];
#pragma unroll
  for (int c = 0; c < 8; ++c)
#pragma unroll
    for (int e = 0; e < 16; ++e) acc[c][e] = 0.f;
  float sumP = 0.f;

  const char* cbase = (const char*)hbuf;
  const int mrow = wv * 32 + lm;

  asm volatile("s_waitcnt vmcnt(0)" ::: "memory");    // reset count base
  SB0;
  STAGE(0, 0);
  SB0;
  STAGE(1, 1);
  SB0;

  // chunk 0 (read par0, gen chunk1 -> par1)
  STEP(0, 0, 2, 1, 4,  0, 0, 0, 1, 0, 1);
  STEP(1, 1, 0, 1, 12, 1, 0, 1, 1, 1, 1);
  STEP(2, 2, 1, 1, 20, 1, 1, 1, 1, 2, 1);
  STEP(3, 0, 2, 1, 20, 1, 2, 1, 1, 3, 1);
  STEP(4, 1, 0, 1, 20, 1, 3, 1, 0, 0, 0);
  STEP(5, 2, 1, 1, 12, 0, 0, 0, 0, 0, 0);
  STEP(6, 0, 2, 1, 4,  0, 0, 0, 0, 0, 0);
  STEP(7, 1, 0, 1, 4,  0, 0, 0, 0, 0, 0);
  // chunk 1 (read par1, gen chunk2 -> par0)
  STEP(8,  2, 1, 1, 4,  0, 0, 0, 1, 0, 2);
  STEP(9,  0, 2, 1, 12, 1, 0, 0, 1, 1, 2);
  STEP(10, 1, 0, 1, 20, 1, 1, 0, 1, 2, 2);
  STEP(11, 2, 1, 1, 20, 1, 2, 0, 1, 3, 2);
  STEP(12, 0, 2, 1, 20, 1, 3, 0, 0, 0, 0);
  STEP(13, 1, 0, 1, 12, 0, 0, 0, 0, 0, 0);
  STEP(14, 2, 1, 1, 4,  0, 0, 0, 0, 0, 0);
  STEP(15, 0, 2, 1, 4,  0, 0, 0, 0, 0, 0);
  // chunk 2 (read par0, gen chunk3 -> par1)
  STEP(16, 1, 0, 1, 4,  0, 0, 0, 1, 0, 3);
  STEP(17, 2, 1, 1, 12, 1, 0, 1, 1, 1, 3);
  STEP(18, 0, 2, 1, 20, 1, 1, 1, 1, 2, 3);
  STEP(19, 1, 0, 1, 20, 1, 2, 1, 1, 3, 3);
  STEP(20, 2, 1, 1, 20, 1, 3, 1, 0, 0, 0);
  STEP(21, 0, 2, 1, 12, 0, 0, 0, 0, 0, 0);
  STEP(22, 1, 0, 1, 4,  0, 0, 0, 0, 0, 0);
  STEP(23, 2, 1, 1, 4,  0, 0, 0, 0, 0, 0);
  // chunk 3 (read par1, no gen)
  STEP(24, 0, 2, 1, 4,  0, 0, 0, 0, 0, 0);
  STEP(25, 1, 0, 1, 4,  0, 0, 0, 0, 0, 0);
  STEP(26, 2, 1, 1, 4,  0, 0, 0, 0, 0, 0);
  STEP(27, 0, 2, 1, 4,  0, 0, 0, 0, 0, 0);
  STEP(28, 1, 0, 1, 4,  0, 0, 0, 0, 0, 0);
  STEP(29, 2, 1, 1, 4,  0, 0, 0, 0, 0, 0);
  STEP(30, 0, 2, 0, 4,  0, 0, 0, 0, 0, 0);
  STEP(31, 1, 0, 0, 0,  0, 0, 0, 0, 0, 0);

#undef SB0
#undef ADJP
#undef CONVP
#undef STAGE
#undef REGEN8
#undef STEP

  // rowsum: lanes l and l^32 hold the two k-halves of row lm
  sumP += __shfl_xor(sumP, 32);
  if (lh == 0) rowsumP[(size_t)ks * NN + rA] = sumP;

  // C-write (bf16 partials): col = c*32+lm; row per C/D layout
  unsigned short* dst = partB + (size_t)ks * NN * FOUT;
  const int rowb = r0 + wv * 32 + 4 * lh;
#pragma unroll
  for (int c = 0; c < 8; ++c) {
    const int col = c * 32 + lm;
#pragma unroll
    for (int reg = 0; reg < 16; ++reg) {
      int row = rowb + (reg & 3) + 8 * (reg >> 2);
      dst[(size_t)row * FOUT + col] = f2bf(acc[c][reg]);
    }
  }
}

// ---------------- K4: sum 8 bf16 K-partials + rowsums, normalize ----------
__global__ __launch_bounds__(256) void k_fin(
    float* __restrict__ outp, const unsigned short* __restrict__ partB,
    const float* __restrict__ rowsumP)
{
  const int idx4 = blockIdx.x * 256 + threadIdx.x;
  const size_t e = (size_t)idx4 * 4;
  const int i = (int)(e >> 8);
  float rs = 0.f;
#pragma unroll
  for (int p = 0; p < 8; ++p) rs += rowsumP[(size_t)p * NN + i];
  float4 o = {0.f, 0.f, 0.f, 0.f};
#pragma unroll
  for (int p = 0; p < 8; ++p) {
    ushort4 pv = *(const ushort4*)(partB + (size_t)p * NN * FOUT + e);
    o.x += bf2f(pv.x); o.y += bf2f(pv.y);
    o.z += bf2f(pv.z); o.w += bf2f(pv.w);
  }
  float inv = 1.f / rs;
  o.x *= inv; o.y *= inv; o.z *= inv; o.w *= inv;
  *(float4*)(outp + e) = o;
}

extern "C" void kernel_launch(void* const* d_in, const int* in_sizes, int n_in,
                              void* d_out, int out_size, void* d_ws, size_t ws_size,
                              hipStream_t stream)
{
  const float* x  = (const float*)d_in[0];
  const int* adj  = (const int*)d_in[1];
  const float* Wm = (const float*)d_in[2];
  const float* aG = (const float*)d_in[3];
  float* outp = (float*)d_out;

  char* w = (char*)d_ws;
  unsigned short* hTt  = (unsigned short*)(w + 0);           // 4 MB (tiled)
  float* f1            = (float*)(w + 4194304);              // 32 KB
  float* f2            = (float*)(w + 4227072);              // 32 KB
  float* mhat          = (float*)(w + 4259840);              // 32 KB
  float* rowsumP       = (float*)(w + 4292608);              // 256 KB
  unsigned short* WtHi = (unsigned short*)(w + 4554752);     // 256 KB
  unsigned short* WtLo = (unsigned short*)(w + 4816896);     // 256 KB
  unsigned short* partB= (unsigned short*)(w + 5079040);     // 32 MB (8 bf16 slices)

  hipLaunchKernelGGL(k_prep,   dim3(32),    dim3(256),  0, stream, Wm, WtHi, WtLo);
  hipLaunchKernelGGL(k_gemm_h, dim3(256),   dim3(256),  0, stream, x, WtHi, WtLo, aG, hTt, f1, f2);
  hipLaunchKernelGGL(k_bound,  dim3(1),     dim3(1024), 0, stream, f1, f2, mhat);
  hipLaunchKernelGGL(k_spmm,   dim3(64, 8), dim3(256),  0, stream, hTt, adj, f1, f2, mhat, partB, rowsumP);
  hipLaunchKernelGGL(k_fin,    dim3(2048),  dim3(256),  0, stream, outp, partB, rowsumP);
}